// Round 4
// baseline (152.407 us; speedup 1.0000x reference)
//
#include <hip/hip_runtime.h>
#include <math.h>

#define HW 16384
#define C_DIM 256
#define V_DIM 6
#define PT 64
#define BK 32
#define KROW 40

typedef short bf16x8 __attribute__((ext_vector_type(8)));
typedef float f32x4 __attribute__((ext_vector_type(4)));

// Truncation-based fp32 -> bf16 hi/lo split: hi = trunc(x), xl = x - hi
// (exact), lo = trunc(xl).  |x - (hi+lo)| <= 2^-16 |x|.
__device__ __forceinline__ void split2(float x, unsigned short& h,
                                       unsigned short& l) {
    unsigned u = __float_as_uint(x);
    h = (unsigned short)(u >> 16);
    float xl = x - __uint_as_float(u & 0xFFFF0000u);
    l = (unsigned short)(__float_as_uint(xl) >> 16);
}

// ---------------------------------------------------------------------------
// K1: M = Wq^T @ Wk, stored as bf16 hi/lo.  4 independent accumulators to
// break the FMA/load dependency chain (was latency-bound).
// ---------------------------------------------------------------------------
__global__ void compute_M_kernel(const float* __restrict__ Wq,
                                 const float* __restrict__ Wk,
                                 unsigned short* __restrict__ Mh,
                                 unsigned short* __restrict__ Ml) {
    const int i = blockIdx.x;     // block-uniform -> Wq reads are scalar loads
    const int j = threadIdx.x;
    float a0 = 0.f, a1 = 0.f, a2 = 0.f, a3 = 0.f;
    #pragma unroll 4
    for (int o = 0; o < C_DIM; o += 4) {
        a0 = fmaf(Wq[(o + 0) * C_DIM + i], Wk[(o + 0) * C_DIM + j], a0);
        a1 = fmaf(Wq[(o + 1) * C_DIM + i], Wk[(o + 1) * C_DIM + j], a1);
        a2 = fmaf(Wq[(o + 2) * C_DIM + i], Wk[(o + 2) * C_DIM + j], a2);
        a3 = fmaf(Wq[(o + 3) * C_DIM + i], Wk[(o + 3) * C_DIM + j], a3);
    }
    float acc = (a0 + a1) + (a2 + a3);
    unsigned short h, l;
    split2(acc, h, l);
    Mh[i * C_DIM + j] = h;
    Ml[i * C_DIM + j] = l;
}

// ---------------------------------------------------------------------------
// K2: score[v][p] = q[v,:,p]^T M k[v,:,p] via 3-term split-bf16 MFMA.
// 256 thr = 4 waves; wave w owns i-rows [64w, 64w+64); pixel tile = 64.
// A-fragments (M hi/lo) read DIRECTLY from global (L2-resident, no LDS).
// K tile double-buffered in LDS; staging thread = (pixel lane-fast, 8
// channels) -> one ds_write_b128 per buffer, start banks cover all 32.
// One barrier per ks; next-tile loads issued before the MFMAs (T14).
// ---------------------------------------------------------------------------
__global__ __launch_bounds__(256) void score_kernel(
        const float* __restrict__ q, const float* __restrict__ k,
        const unsigned short* __restrict__ Mh,
        const unsigned short* __restrict__ Ml,
        float* __restrict__ score) {
    const int tid  = threadIdx.x;
    const int lane = tid & 63;
    const int w    = tid >> 6;
    const int pt   = blockIdx.x & 255;
    const int v    = blockIdx.x >> 8;
    const int gp0  = pt * PT;
    const int l15  = lane & 15;
    const int l4   = lane >> 4;
    const int p_s  = tid & 63;          // staging pixel (lane-fast)
    const int jg   = tid >> 6;          // staging channel group (8 ch)

    __shared__ __align__(16) unsigned short Kh_s[2][PT * KROW];  // 2x5 KB
    __shared__ __align__(16) unsigned short Kl_s[2][PT * KROW];  // 2x5 KB
    __shared__ float s_red[4][PT];                               // 1 KB

    const float* kv = k + (size_t)v * C_DIM * HW + gp0;
    const float* qv = q + (size_t)v * C_DIM * HW + gp0;

    f32x4 acc[4][4];
    #pragma unroll
    for (int a = 0; a < 4; ++a)
        #pragma unroll
        for (int b = 0; b < 4; ++b)
            acc[a][b] = (f32x4){0.f, 0.f, 0.f, 0.f};

    // ---- prologue: stage ks=0 into buffer 0 ----
    {
        const float* kp = kv + (size_t)(jg * 8) * HW + p_s;
        float x[8];
        #pragma unroll
        for (int e = 0; e < 8; ++e) x[e] = kp[(size_t)e * HW];
        unsigned short h[8], l[8];
        #pragma unroll
        for (int e = 0; e < 8; ++e) split2(x[e], h[e], l[e]);
        uint4 H, L;
        H.x = (unsigned)h[0] | ((unsigned)h[1] << 16);
        H.y = (unsigned)h[2] | ((unsigned)h[3] << 16);
        H.z = (unsigned)h[4] | ((unsigned)h[5] << 16);
        H.w = (unsigned)h[6] | ((unsigned)h[7] << 16);
        L.x = (unsigned)l[0] | ((unsigned)l[1] << 16);
        L.y = (unsigned)l[2] | ((unsigned)l[3] << 16);
        L.z = (unsigned)l[4] | ((unsigned)l[5] << 16);
        L.w = (unsigned)l[6] | ((unsigned)l[7] << 16);
        *(uint4*)&Kh_s[0][p_s * KROW + jg * 8] = H;
        *(uint4*)&Kl_s[0][p_s * KROW + jg * 8] = L;
    }
    __syncthreads();

    const int ibase = w * 64;

    for (int ks = 0; ks < C_DIM / BK; ++ks) {
        const int cur = ks & 1;

        // (1) issue next K-tile global loads (latency hides under MFMA)
        float x[8];
        if (ks < 7) {
            const float* kp = kv + (size_t)((ks + 1) * BK + jg * 8) * HW + p_s;
            #pragma unroll
            for (int e = 0; e < 8; ++e) x[e] = kp[(size_t)e * HW];
        }

        // (2) A fragments straight from global (M is L2-hot, 16B/lane)
        bf16x8 Ah[4], Al[4];
        #pragma unroll
        for (int it = 0; it < 4; ++it) {
            int row = ibase + it * 16 + l15;
            Ah[it] = *(const bf16x8*)(Mh + (size_t)row * C_DIM + ks * BK + l4 * 8);
            Al[it] = *(const bf16x8*)(Ml + (size_t)row * C_DIM + ks * BK + l4 * 8);
        }

        // (3) B fragments from LDS (conflict-free b128 reads)
        bf16x8 Bh[4], Bl[4];
        #pragma unroll
        for (int jt = 0; jt < 4; ++jt) {
            int bp = jt * 16 + l15;
            Bh[jt] = *(const bf16x8*)&Kh_s[cur][bp * KROW + l4 * 8];
            Bl[jt] = *(const bf16x8*)&Kl_s[cur][bp * KROW + l4 * 8];
        }

        // (4) 3-term MFMA
        #pragma unroll
        for (int it = 0; it < 4; ++it)
            #pragma unroll
            for (int jt = 0; jt < 4; ++jt) {
                acc[it][jt] = __builtin_amdgcn_mfma_f32_16x16x32_bf16(
                                  Ah[it], Bh[jt], acc[it][jt], 0, 0, 0);
                acc[it][jt] = __builtin_amdgcn_mfma_f32_16x16x32_bf16(
                                  Ah[it], Bl[jt], acc[it][jt], 0, 0, 0);
                acc[it][jt] = __builtin_amdgcn_mfma_f32_16x16x32_bf16(
                                  Al[it], Bh[jt], acc[it][jt], 0, 0, 0);
            }

        // (5) split + write next buffer (loads have drained under the MFMAs)
        if (ks < 7) {
            unsigned short h[8], l[8];
            #pragma unroll
            for (int e = 0; e < 8; ++e) split2(x[e], h[e], l[e]);
            uint4 H, L;
            H.x = (unsigned)h[0] | ((unsigned)h[1] << 16);
            H.y = (unsigned)h[2] | ((unsigned)h[3] << 16);
            H.z = (unsigned)h[4] | ((unsigned)h[5] << 16);
            H.w = (unsigned)h[6] | ((unsigned)h[7] << 16);
            L.x = (unsigned)l[0] | ((unsigned)l[1] << 16);
            L.y = (unsigned)l[2] | ((unsigned)l[3] << 16);
            L.z = (unsigned)l[4] | ((unsigned)l[5] << 16);
            L.w = (unsigned)l[6] | ((unsigned)l[7] << 16);
            *(uint4*)&Kh_s[cur ^ 1][p_s * KROW + jg * 8] = H;
            *(uint4*)&Kl_s[cur ^ 1][p_s * KROW + jg * 8] = L;
        }
        __syncthreads();
    }

    // ---- epilogue: sp[p] = sum_i q[i,p] * T[i,p] ----
    float sp[4];
    #pragma unroll
    for (int jt = 0; jt < 4; ++jt) sp[jt] = 0.f;
    #pragma unroll
    for (int jt = 0; jt < 4; ++jt) {
        #pragma unroll
        for (int it = 0; it < 4; ++it) {
            int irow = ibase + it * 16 + l4 * 4;
            const float* qp = qv + (size_t)irow * HW + jt * 16 + l15;
            #pragma unroll
            for (int r = 0; r < 4; ++r)
                sp[jt] = fmaf(qp[(size_t)r * HW], acc[it][jt][r], sp[jt]);
        }
        sp[jt] += __shfl_xor(sp[jt], 16, 64);
        sp[jt] += __shfl_xor(sp[jt], 32, 64);
    }
    if (lane < 16) {
        #pragma unroll
        for (int jt = 0; jt < 4; ++jt)
            s_red[w][jt * 16 + lane] = sp[jt];
    }
    __syncthreads();
    if (tid < PT) {
        score[v * HW + gp0 + tid] =
            s_red[0][tid] + s_red[1][tid] + s_red[2][tid] + s_red[3][tid];
    }
}

// ---------------------------------------------------------------------------
// K3: in-place softmax over views.
// ---------------------------------------------------------------------------
__global__ __launch_bounds__(256) void softmax_w_kernel(float* __restrict__ score) {
    const int p = blockIdx.x * 256 + threadIdx.x;
    float s[V_DIM];
    float mx = -1e30f;
    #pragma unroll
    for (int vv = 0; vv < V_DIM; ++vv) {
        s[vv] = score[vv * HW + p];
        mx = fmaxf(mx, s[vv]);
    }
    float sum = 0.f;
    #pragma unroll
    for (int vv = 0; vv < V_DIM; ++vv) {
        s[vv] = __expf(s[vv] - mx);
        sum += s[vv];
    }
    float inv = 1.0f / sum;
    #pragma unroll
    for (int vv = 0; vv < V_DIM; ++vv)
        score[vv * HW + p] = s[vv] * inv;
}

// ---------------------------------------------------------------------------
// K4: split Wv into bf16 hi/lo (reuses the Mh/Ml workspace).
// ---------------------------------------------------------------------------
__global__ void wsplit_kernel(const float* __restrict__ Wv,
                              unsigned short* __restrict__ Wvh,
                              unsigned short* __restrict__ Wvl) {
    const int i = blockIdx.x;
    const int j = threadIdx.x;
    unsigned short h, l;
    split2(Wv[i * C_DIM + j], h, l);
    Wvh[i * C_DIM + j] = h;
    Wvl[i * C_DIM + j] = l;
}

// ---------------------------------------------------------------------------
// K5: out = Wv @ vbar, vbar[c][p] = sum_v w[v][p] * v[v][c][p].
// 512 thr = 8 waves; wave w owns o-rows [32w, 32w+32); pixel tile = 64.
// Wv fragments direct from global; X tile double-buffered; softmax weights
// held in registers; v read exactly once, coalesced.
// ---------------------------------------------------------------------------
__global__ __launch_bounds__(512) void out_gemm_kernel(
        const float* __restrict__ vin,
        const unsigned short* __restrict__ Wvh,
        const unsigned short* __restrict__ Wvl,
        const float* __restrict__ wsm,
        float* __restrict__ out) {
    const int tid  = threadIdx.x;
    const int lane = tid & 63;
    const int w    = tid >> 6;          // 0..7
    const int gp0  = blockIdx.x * PT;
    const int l15  = lane & 15;
    const int l4   = lane >> 4;
    const int p_s  = tid & 63;          // staging pixel (lane-fast)
    const int jg   = tid >> 6;          // staging channel group (4 ch)

    __shared__ __align__(16) unsigned short Xh_s[2][PT * KROW];
    __shared__ __align__(16) unsigned short Xl_s[2][PT * KROW];

    float wr[V_DIM];
    #pragma unroll
    for (int vv = 0; vv < V_DIM; ++vv) wr[vv] = wsm[vv * HW + gp0 + p_s];

    const float* vbase = vin + gp0 + p_s;

    f32x4 acc[2][4];
    #pragma unroll
    for (int a = 0; a < 2; ++a)
        #pragma unroll
        for (int b = 0; b < 4; ++b)
            acc[a][b] = (f32x4){0.f, 0.f, 0.f, 0.f};

    // ---- prologue: stage ks=0 into buffer 0 ----
    {
        float xv[4][V_DIM];
        #pragma unroll
        for (int vv = 0; vv < V_DIM; ++vv)
            #pragma unroll
            for (int e = 0; e < 4; ++e)
                xv[e][vv] = vbase[(size_t)(vv * C_DIM + jg * 4 + e) * HW];
        unsigned short h[4], l[4];
        #pragma unroll
        for (int e = 0; e < 4; ++e) {
            float s = 0.f;
            #pragma unroll
            for (int vv = 0; vv < V_DIM; ++vv) s = fmaf(wr[vv], xv[e][vv], s);
            split2(s, h[e], l[e]);
        }
        uint2 H, L;
        H.x = (unsigned)h[0] | ((unsigned)h[1] << 16);
        H.y = (unsigned)h[2] | ((unsigned)h[3] << 16);
        L.x = (unsigned)l[0] | ((unsigned)l[1] << 16);
        L.y = (unsigned)l[2] | ((unsigned)l[3] << 16);
        *(uint2*)&Xh_s[0][p_s * KROW + jg * 4] = H;
        *(uint2*)&Xl_s[0][p_s * KROW + jg * 4] = L;
    }
    __syncthreads();

    const int obase = w * 32;

    for (int ks = 0; ks < C_DIM / BK; ++ks) {
        const int cur = ks & 1;

        // (1) issue next v loads
        float xv[4][V_DIM];
        if (ks < 7) {
            #pragma unroll
            for (int vv = 0; vv < V_DIM; ++vv)
                #pragma unroll
                for (int e = 0; e < 4; ++e)
                    xv[e][vv] = vbase[(size_t)(vv * C_DIM + (ks + 1) * BK +
                                               jg * 4 + e) * HW];
        }

        // (2) A fragments from global (Wv hi/lo, L2-hot)
        bf16x8 Ah[2], Al[2];
        #pragma unroll
        for (int it = 0; it < 2; ++it) {
            int row = obase + it * 16 + l15;
            Ah[it] = *(const bf16x8*)(Wvh + (size_t)row * C_DIM + ks * BK + l4 * 8);
            Al[it] = *(const bf16x8*)(Wvl + (size_t)row * C_DIM + ks * BK + l4 * 8);
        }

        // (3) B fragments from LDS
        bf16x8 Bh[4], Bl[4];
        #pragma unroll
        for (int jt = 0; jt < 4; ++jt) {
            int bp = jt * 16 + l15;
            Bh[jt] = *(const bf16x8*)&Xh_s[cur][bp * KROW + l4 * 8];
            Bl[jt] = *(const bf16x8*)&Xl_s[cur][bp * KROW + l4 * 8];
        }

        // (4) 3-term MFMA
        #pragma unroll
        for (int it = 0; it < 2; ++it)
            #pragma unroll
            for (int jt = 0; jt < 4; ++jt) {
                acc[it][jt] = __builtin_amdgcn_mfma_f32_16x16x32_bf16(
                                  Ah[it], Bh[jt], acc[it][jt], 0, 0, 0);
                acc[it][jt] = __builtin_amdgcn_mfma_f32_16x16x32_bf16(
                                  Ah[it], Bl[jt], acc[it][jt], 0, 0, 0);
                acc[it][jt] = __builtin_amdgcn_mfma_f32_16x16x32_bf16(
                                  Al[it], Bh[jt], acc[it][jt], 0, 0, 0);
            }

        // (5) weighted-sum + split + write next buffer
        if (ks < 7) {
            unsigned short h[4], l[4];
            #pragma unroll
            for (int e = 0; e < 4; ++e) {
                float s = 0.f;
                #pragma unroll
                for (int vv = 0; vv < V_DIM; ++vv) s = fmaf(wr[vv], xv[e][vv], s);
                split2(s, h[e], l[e]);
            }
            uint2 H, L;
            H.x = (unsigned)h[0] | ((unsigned)h[1] << 16);
            H.y = (unsigned)h[2] | ((unsigned)h[3] << 16);
            L.x = (unsigned)l[0] | ((unsigned)l[1] << 16);
            L.y = (unsigned)l[2] | ((unsigned)l[3] << 16);
            *(uint2*)&Xh_s[cur ^ 1][p_s * KROW + jg * 4] = H;
            *(uint2*)&Xl_s[cur ^ 1][p_s * KROW + jg * 4] = L;
        }
        __syncthreads();
    }

    // ---- store D tile: o = obase + it*16 + l4*4 + r, p = jt*16 + l15 ----
    #pragma unroll
    for (int it = 0; it < 2; ++it)
        #pragma unroll
        for (int jt = 0; jt < 4; ++jt)
            #pragma unroll
            for (int r = 0; r < 4; ++r) {
                int o = obase + it * 16 + l4 * 4 + r;
                out[(size_t)o * HW + gp0 + jt * 16 + l15] = acc[it][jt][r];
            }
}

// ---------------------------------------------------------------------------
extern "C" void kernel_launch(void* const* d_in, const int* in_sizes, int n_in,
                              void* d_out, int out_size, void* d_ws, size_t ws_size,
                              hipStream_t stream) {
    const float* q  = (const float*)d_in[0];
    const float* k  = (const float*)d_in[1];
    const float* v  = (const float*)d_in[2];
    const float* Wq = (const float*)d_in[3];
    const float* Wk = (const float*)d_in[4];
    const float* Wv = (const float*)d_in[5];
    float* out = (float*)d_out;

    unsigned short* Mh = (unsigned short*)d_ws;          // 128 KB (later: Wvh)
    unsigned short* Ml = Mh + C_DIM * C_DIM;             // 128 KB (later: Wvl)
    float* score = (float*)(Ml + C_DIM * C_DIM);         // 384 KB (-> weights)

    compute_M_kernel<<<C_DIM, C_DIM, 0, stream>>>(Wq, Wk, Mh, Ml);
    score_kernel<<<V_DIM * 256, 256, 0, stream>>>(q, k, Mh, Ml, score);
    softmax_w_kernel<<<HW / 256, 256, 0, stream>>>(score);
    wsplit_kernel<<<C_DIM, C_DIM, 0, stream>>>(Wv, Mh, Ml);
    out_gemm_kernel<<<HW / PT, 512, 0, stream>>>(v, Mh, Ml, score, out);
}

// Round 5
// 139.935 us; speedup vs baseline: 1.0891x; 1.0891x over previous
//
#include <hip/hip_runtime.h>
#include <math.h>

#define HW 16384
#define C_DIM 256
#define V_DIM 6
#define PT 64
#define BK 32
#define KROW 40

typedef short bf16x8 __attribute__((ext_vector_type(8)));
typedef float f32x4 __attribute__((ext_vector_type(4)));

// fp32 -> bf16 hi/lo split (truncation). |x - (hi+lo)| <= 2^-16 |x|.
__device__ __forceinline__ void split2(float x, unsigned short& h,
                                       unsigned short& l) {
    unsigned u = __float_as_uint(x);
    h = (unsigned short)(u >> 16);
    float xl = x - __uint_as_float(u & 0xFFFF0000u);
    l = (unsigned short)(__float_as_uint(xl) >> 16);
}

// ---------------------------------------------------------------------------
// K1: M = Wq^T @ Wk, stored as bf16 hi/lo.
// ---------------------------------------------------------------------------
__global__ void compute_M_kernel(const float* __restrict__ Wq,
                                 const float* __restrict__ Wk,
                                 unsigned short* __restrict__ Mh,
                                 unsigned short* __restrict__ Ml) {
    const int i = blockIdx.x;
    const int j = threadIdx.x;
    float a0 = 0.f, a1 = 0.f, a2 = 0.f, a3 = 0.f;
    #pragma unroll 4
    for (int o = 0; o < C_DIM; o += 4) {
        a0 = fmaf(Wq[(o + 0) * C_DIM + i], Wk[(o + 0) * C_DIM + j], a0);
        a1 = fmaf(Wq[(o + 1) * C_DIM + i], Wk[(o + 1) * C_DIM + j], a1);
        a2 = fmaf(Wq[(o + 2) * C_DIM + i], Wk[(o + 2) * C_DIM + j], a2);
        a3 = fmaf(Wq[(o + 3) * C_DIM + i], Wk[(o + 3) * C_DIM + j], a3);
    }
    float acc = (a0 + a1) + (a2 + a3);
    unsigned short h, l;
    split2(acc, h, l);
    Mh[i * C_DIM + j] = h;
    Ml[i * C_DIM + j] = l;
}

// ---------------------------------------------------------------------------
// K2: score[v][p] = q[v,:,p]^T M k[v,:,p], 3-term split-bf16 MFMA.
// 256 thr = 4 waves; wave w owns i-rows [64w, 64w+64); pixel tile = 64.
// A-fragments (M hi/lo) from global/L2, REGISTER-PIPELINED one ks ahead
// (round-4 loaded them in-loop -> vmcnt stall every ks; this hides it).
// K tile double-buffered in LDS, conflict-free b128 staging, 1 barrier/ks.
// MFMA emitted term-outer (acc reuse distance 16).
// ---------------------------------------------------------------------------
__global__ __launch_bounds__(256, 2) void score_kernel(
        const float* __restrict__ q, const float* __restrict__ k,
        const unsigned short* __restrict__ Mh,
        const unsigned short* __restrict__ Ml,
        float* __restrict__ score) {
    const int tid  = threadIdx.x;
    const int lane = tid & 63;
    const int w    = tid >> 6;
    const int pt   = blockIdx.x & 255;
    const int v    = blockIdx.x >> 8;
    const int gp0  = pt * PT;
    const int l15  = lane & 15;
    const int l4   = lane >> 4;
    const int p_s  = tid & 63;          // staging pixel (lane-fast)
    const int jg   = tid >> 6;          // staging channel group (8 ch)

    __shared__ __align__(16) unsigned short Kh_s[2][PT * KROW];  // 2x5 KB
    __shared__ __align__(16) unsigned short Kl_s[2][PT * KROW];  // 2x5 KB
    __shared__ float s_red[4][PT];

    const float* kv = k + (size_t)v * C_DIM * HW + gp0;
    const float* qv = q + (size_t)v * C_DIM * HW + gp0;
    const int ibase = w * 64;

    f32x4 acc[4][4];
    #pragma unroll
    for (int a = 0; a < 4; ++a)
        #pragma unroll
        for (int b = 0; b < 4; ++b)
            acc[a][b] = (f32x4){0.f, 0.f, 0.f, 0.f};

    // A pipeline registers: [pipe][it], pipe toggles per ks (static after
    // full unroll).
    bf16x8 Ah[2][4], Al[2][4];

    // ---- prologue: stage K(ks=0) into buf 0; load A(ks=0) into pipe 0 ----
    {
        const float* kp = kv + (size_t)(jg * 8) * HW + p_s;
        float x[8];
        #pragma unroll
        for (int e = 0; e < 8; ++e) x[e] = kp[(size_t)e * HW];
        unsigned short h[8], l[8];
        #pragma unroll
        for (int e = 0; e < 8; ++e) split2(x[e], h[e], l[e]);
        uint4 H, L;
        H.x = (unsigned)h[0] | ((unsigned)h[1] << 16);
        H.y = (unsigned)h[2] | ((unsigned)h[3] << 16);
        H.z = (unsigned)h[4] | ((unsigned)h[5] << 16);
        H.w = (unsigned)h[6] | ((unsigned)h[7] << 16);
        L.x = (unsigned)l[0] | ((unsigned)l[1] << 16);
        L.y = (unsigned)l[2] | ((unsigned)l[3] << 16);
        L.z = (unsigned)l[4] | ((unsigned)l[5] << 16);
        L.w = (unsigned)l[6] | ((unsigned)l[7] << 16);
        *(uint4*)&Kh_s[0][p_s * KROW + jg * 8] = H;
        *(uint4*)&Kl_s[0][p_s * KROW + jg * 8] = L;

        #pragma unroll
        for (int it = 0; it < 4; ++it) {
            int row = ibase + it * 16 + l15;
            Ah[0][it] = *(const bf16x8*)(Mh + (size_t)row * C_DIM + l4 * 8);
            Al[0][it] = *(const bf16x8*)(Ml + (size_t)row * C_DIM + l4 * 8);
        }
    }
    __syncthreads();

    #pragma unroll
    for (int ks = 0; ks < 8; ++ks) {
        const int cur = ks & 1;

        // (1) prefetch next K tile (consumed at (4)) and next A fragments
        //     (consumed NEXT iteration, after the barrier).
        float x[8];
        if (ks < 7) {
            const float* kp = kv + (size_t)((ks + 1) * BK + jg * 8) * HW + p_s;
            #pragma unroll
            for (int e = 0; e < 8; ++e) x[e] = kp[(size_t)e * HW];
            #pragma unroll
            for (int it = 0; it < 4; ++it) {
                int row = ibase + it * 16 + l15;
                Ah[cur ^ 1][it] = *(const bf16x8*)(Mh + (size_t)row * C_DIM +
                                                   (ks + 1) * BK + l4 * 8);
                Al[cur ^ 1][it] = *(const bf16x8*)(Ml + (size_t)row * C_DIM +
                                                   (ks + 1) * BK + l4 * 8);
            }
        }

        // (2) B fragments from LDS
        bf16x8 Bh[4], Bl[4];
        #pragma unroll
        for (int jt = 0; jt < 4; ++jt) {
            int bp = jt * 16 + l15;
            Bh[jt] = *(const bf16x8*)&Kh_s[cur][bp * KROW + l4 * 8];
            Bl[jt] = *(const bf16x8*)&Kl_s[cur][bp * KROW + l4 * 8];
        }

        // (3) MFMAs, term-outer (acc dependency distance = 16)
        #pragma unroll
        for (int it = 0; it < 4; ++it)
            #pragma unroll
            for (int jt = 0; jt < 4; ++jt)
                acc[it][jt] = __builtin_amdgcn_mfma_f32_16x16x32_bf16(
                                  Ah[cur][it], Bh[jt], acc[it][jt], 0, 0, 0);
        #pragma unroll
        for (int it = 0; it < 4; ++it)
            #pragma unroll
            for (int jt = 0; jt < 4; ++jt)
                acc[it][jt] = __builtin_amdgcn_mfma_f32_16x16x32_bf16(
                                  Ah[cur][it], Bl[jt], acc[it][jt], 0, 0, 0);
        #pragma unroll
        for (int it = 0; it < 4; ++it)
            #pragma unroll
            for (int jt = 0; jt < 4; ++jt)
                acc[it][jt] = __builtin_amdgcn_mfma_f32_16x16x32_bf16(
                                  Al[cur][it], Bh[jt], acc[it][jt], 0, 0, 0);

        // (4) split + write next K buffer
        if (ks < 7) {
            unsigned short h[8], l[8];
            #pragma unroll
            for (int e = 0; e < 8; ++e) split2(x[e], h[e], l[e]);
            uint4 H, L;
            H.x = (unsigned)h[0] | ((unsigned)h[1] << 16);
            H.y = (unsigned)h[2] | ((unsigned)h[3] << 16);
            H.z = (unsigned)h[4] | ((unsigned)h[5] << 16);
            H.w = (unsigned)h[6] | ((unsigned)h[7] << 16);
            L.x = (unsigned)l[0] | ((unsigned)l[1] << 16);
            L.y = (unsigned)l[2] | ((unsigned)l[3] << 16);
            L.z = (unsigned)l[4] | ((unsigned)l[5] << 16);
            L.w = (unsigned)l[6] | ((unsigned)l[7] << 16);
            *(uint4*)&Kh_s[cur ^ 1][p_s * KROW + jg * 8] = H;
            *(uint4*)&Kl_s[cur ^ 1][p_s * KROW + jg * 8] = L;
        }
        __syncthreads();
    }

    // ---- epilogue: sp[p] = sum_i q[i,p] * T[i,p] ----
    float sp[4];
    #pragma unroll
    for (int jt = 0; jt < 4; ++jt) sp[jt] = 0.f;
    #pragma unroll
    for (int jt = 0; jt < 4; ++jt) {
        #pragma unroll
        for (int it = 0; it < 4; ++it) {
            int irow = ibase + it * 16 + l4 * 4;
            const float* qp = qv + (size_t)irow * HW + jt * 16 + l15;
            #pragma unroll
            for (int r = 0; r < 4; ++r)
                sp[jt] = fmaf(qp[(size_t)r * HW], acc[it][jt][r], sp[jt]);
        }
        sp[jt] += __shfl_xor(sp[jt], 16, 64);
        sp[jt] += __shfl_xor(sp[jt], 32, 64);
    }
    if (lane < 16) {
        #pragma unroll
        for (int jt = 0; jt < 4; ++jt)
            s_red[w][jt * 16 + lane] = sp[jt];
    }
    __syncthreads();
    if (tid < PT) {
        score[v * HW + gp0 + tid] =
            s_red[0][tid] + s_red[1][tid] + s_red[2][tid] + s_red[3][tid];
    }
}

// ---------------------------------------------------------------------------
// K3: in-place softmax over views.
// ---------------------------------------------------------------------------
__global__ __launch_bounds__(256) void softmax_w_kernel(float* __restrict__ score) {
    const int p = blockIdx.x * 256 + threadIdx.x;
    float s[V_DIM];
    float mx = -1e30f;
    #pragma unroll
    for (int vv = 0; vv < V_DIM; ++vv) {
        s[vv] = score[vv * HW + p];
        mx = fmaxf(mx, s[vv]);
    }
    float sum = 0.f;
    #pragma unroll
    for (int vv = 0; vv < V_DIM; ++vv) {
        s[vv] = __expf(s[vv] - mx);
        sum += s[vv];
    }
    float inv = 1.0f / sum;
    #pragma unroll
    for (int vv = 0; vv < V_DIM; ++vv)
        score[vv * HW + p] = s[vv] * inv;
}

// ---------------------------------------------------------------------------
// K4: split Wv into bf16 hi/lo (reuses the Mh/Ml workspace; stream order
// guarantees score_kernel is done with M).
// ---------------------------------------------------------------------------
__global__ void wsplit_kernel(const float* __restrict__ Wv,
                              unsigned short* __restrict__ Wvh,
                              unsigned short* __restrict__ Wvl) {
    const int i = blockIdx.x;
    const int j = threadIdx.x;
    unsigned short h, l;
    split2(Wv[i * C_DIM + j], h, l);
    Wvh[i * C_DIM + j] = h;
    Wvl[i * C_DIM + j] = l;
}

// ---------------------------------------------------------------------------
// K5: out = Wv @ vbar, vbar[c][p] = sum_v w[v][p]*v[v][c][p].
// 512 thr = 8 waves; wave w owns o-rows [32w,32w+32); pixel tile 64.
// Wv fragments register-pipelined one ks ahead; X double-buffered in LDS.
// ---------------------------------------------------------------------------
__global__ __launch_bounds__(512, 2) void out_gemm_kernel(
        const float* __restrict__ vin,
        const unsigned short* __restrict__ Wvh,
        const unsigned short* __restrict__ Wvl,
        const float* __restrict__ wsm,
        float* __restrict__ out) {
    const int tid  = threadIdx.x;
    const int lane = tid & 63;
    const int w    = tid >> 6;          // 0..7
    const int gp0  = blockIdx.x * PT;
    const int l15  = lane & 15;
    const int l4   = lane >> 4;
    const int p_s  = tid & 63;          // staging pixel (lane-fast)
    const int jg   = tid >> 6;          // staging channel group (4 ch)

    __shared__ __align__(16) unsigned short Xh_s[2][PT * KROW];
    __shared__ __align__(16) unsigned short Xl_s[2][PT * KROW];

    float wr[V_DIM];
    #pragma unroll
    for (int vv = 0; vv < V_DIM; ++vv) wr[vv] = wsm[vv * HW + gp0 + p_s];

    const float* vbase = vin + gp0 + p_s;
    const int obase = w * 32;

    f32x4 acc[2][4];
    #pragma unroll
    for (int a = 0; a < 2; ++a)
        #pragma unroll
        for (int b = 0; b < 4; ++b)
            acc[a][b] = (f32x4){0.f, 0.f, 0.f, 0.f};

    bf16x8 Ah[2][2], Al[2][2];

    // ---- prologue ----
    {
        float xv[4][V_DIM];
        #pragma unroll
        for (int vv = 0; vv < V_DIM; ++vv)
            #pragma unroll
            for (int e = 0; e < 4; ++e)
                xv[e][vv] = vbase[(size_t)(vv * C_DIM + jg * 4 + e) * HW];
        unsigned short h[4], l[4];
        #pragma unroll
        for (int e = 0; e < 4; ++e) {
            float s = 0.f;
            #pragma unroll
            for (int vv = 0; vv < V_DIM; ++vv) s = fmaf(wr[vv], xv[e][vv], s);
            split2(s, h[e], l[e]);
        }
        uint2 H, L;
        H.x = (unsigned)h[0] | ((unsigned)h[1] << 16);
        H.y = (unsigned)h[2] | ((unsigned)h[3] << 16);
        L.x = (unsigned)l[0] | ((unsigned)l[1] << 16);
        L.y = (unsigned)l[2] | ((unsigned)l[3] << 16);
        *(uint2*)&Xh_s[0][p_s * KROW + jg * 4] = H;
        *(uint2*)&Xl_s[0][p_s * KROW + jg * 4] = L;

        #pragma unroll
        for (int it = 0; it < 2; ++it) {
            int row = obase + it * 16 + l15;
            Ah[0][it] = *(const bf16x8*)(Wvh + (size_t)row * C_DIM + l4 * 8);
            Al[0][it] = *(const bf16x8*)(Wvl + (size_t)row * C_DIM + l4 * 8);
        }
    }
    __syncthreads();

    #pragma unroll
    for (int ks = 0; ks < 8; ++ks) {
        const int cur = ks & 1;

        // (1) prefetch next v-tile and next Wv fragments
        float xv[4][V_DIM];
        if (ks < 7) {
            #pragma unroll
            for (int vv = 0; vv < V_DIM; ++vv)
                #pragma unroll
                for (int e = 0; e < 4; ++e)
                    xv[e][vv] = vbase[(size_t)(vv * C_DIM + (ks + 1) * BK +
                                               jg * 4 + e) * HW];
            #pragma unroll
            for (int it = 0; it < 2; ++it) {
                int row = obase + it * 16 + l15;
                Ah[cur ^ 1][it] = *(const bf16x8*)(Wvh + (size_t)row * C_DIM +
                                                   (ks + 1) * BK + l4 * 8);
                Al[cur ^ 1][it] = *(const bf16x8*)(Wvl + (size_t)row * C_DIM +
                                                   (ks + 1) * BK + l4 * 8);
            }
        }

        // (2) B fragments from LDS
        bf16x8 Bh[4], Bl[4];
        #pragma unroll
        for (int jt = 0; jt < 4; ++jt) {
            int bp = jt * 16 + l15;
            Bh[jt] = *(const bf16x8*)&Xh_s[cur][bp * KROW + l4 * 8];
            Bl[jt] = *(const bf16x8*)&Xl_s[cur][bp * KROW + l4 * 8];
        }

        // (3) MFMAs, term-outer
        #pragma unroll
        for (int it = 0; it < 2; ++it)
            #pragma unroll
            for (int jt = 0; jt < 4; ++jt)
                acc[it][jt] = __builtin_amdgcn_mfma_f32_16x16x32_bf16(
                                  Ah[cur][it], Bh[jt], acc[it][jt], 0, 0, 0);
        #pragma unroll
        for (int it = 0; it < 2; ++it)
            #pragma unroll
            for (int jt = 0; jt < 4; ++jt)
                acc[it][jt] = __builtin_amdgcn_mfma_f32_16x16x32_bf16(
                                  Ah[cur][it], Bl[jt], acc[it][jt], 0, 0, 0);
        #pragma unroll
        for (int it = 0; it < 2; ++it)
            #pragma unroll
            for (int jt = 0; jt < 4; ++jt)
                acc[it][jt] = __builtin_amdgcn_mfma_f32_16x16x32_bf16(
                                  Al[cur][it], Bh[jt], acc[it][jt], 0, 0, 0);

        // (4) weighted-sum + split + write next buffer
        if (ks < 7) {
            unsigned short h[4], l[4];
            #pragma unroll
            for (int e = 0; e < 4; ++e) {
                float s = 0.f;
                #pragma unroll
                for (int vv = 0; vv < V_DIM; ++vv) s = fmaf(wr[vv], xv[e][vv], s);
                split2(s, h[e], l[e]);
            }
            uint2 H, L;
            H.x = (unsigned)h[0] | ((unsigned)h[1] << 16);
            H.y = (unsigned)h[2] | ((unsigned)h[3] << 16);
            L.x = (unsigned)l[0] | ((unsigned)l[1] << 16);
            L.y = (unsigned)l[2] | ((unsigned)l[3] << 16);
            *(uint2*)&Xh_s[cur ^ 1][p_s * KROW + jg * 4] = H;
            *(uint2*)&Xl_s[cur ^ 1][p_s * KROW + jg * 4] = L;
        }
        __syncthreads();
    }

    // ---- store D tile ----
    #pragma unroll
    for (int it = 0; it < 2; ++it)
        #pragma unroll
        for (int jt = 0; jt < 4; ++jt)
            #pragma unroll
            for (int r = 0; r < 4; ++r) {
                int o = obase + it * 16 + l4 * 4 + r;
                out[(size_t)o * HW + gp0 + jt * 16 + l15] = acc[it][jt][r];
            }
}

// ---------------------------------------------------------------------------
extern "C" void kernel_launch(void* const* d_in, const int* in_sizes, int n_in,
                              void* d_out, int out_size, void* d_ws, size_t ws_size,
                              hipStream_t stream) {
    const float* q  = (const float*)d_in[0];
    const float* k  = (const float*)d_in[1];
    const float* v  = (const float*)d_in[2];
    const float* Wq = (const float*)d_in[3];
    const float* Wk = (const float*)d_in[4];
    const float* Wv = (const float*)d_in[5];
    float* out = (float*)d_out;

    unsigned short* Mh = (unsigned short*)d_ws;          // 128 KB (later: Wvh)
    unsigned short* Ml = Mh + C_DIM * C_DIM;             // 128 KB (later: Wvl)
    float* score = (float*)(Ml + C_DIM * C_DIM);         // 384 KB (-> weights)

    compute_M_kernel<<<C_DIM, C_DIM, 0, stream>>>(Wq, Wk, Mh, Ml);
    score_kernel<<<V_DIM * 256, 256, 0, stream>>>(q, k, Mh, Ml, score);
    softmax_w_kernel<<<HW / 256, 256, 0, stream>>>(score);
    wsplit_kernel<<<C_DIM, C_DIM, 0, stream>>>(Wv, Mh, Ml);
    out_gemm_kernel<<<HW / PT, 512, 0, stream>>>(v, Mh, Ml, score, out);
}

// Round 6
// 136.648 us; speedup vs baseline: 1.1153x; 1.0241x over previous
//
#include <hip/hip_runtime.h>
#include <math.h>

#define HW 16384
#define C_DIM 256
#define V_DIM 6
#define PT 64
#define BK 32
#define KROW 40

typedef short bf16x8 __attribute__((ext_vector_type(8)));
typedef float f32x4 __attribute__((ext_vector_type(4)));

// fp32 -> bf16 hi/lo split (truncation). |x - (hi+lo)| <= 2^-16 |x|.
__device__ __forceinline__ void split2(float x, unsigned short& h,
                                       unsigned short& l) {
    unsigned u = __float_as_uint(x);
    h = (unsigned short)(u >> 16);
    float xl = x - __uint_as_float(u & 0xFFFF0000u);
    l = (unsigned short)(__float_as_uint(xl) >> 16);
}

// ---------------------------------------------------------------------------
// K1: M = Wq^T @ Wk, stored as bf16 hi/lo.
// ---------------------------------------------------------------------------
__global__ void compute_M_kernel(const float* __restrict__ Wq,
                                 const float* __restrict__ Wk,
                                 unsigned short* __restrict__ Mh,
                                 unsigned short* __restrict__ Ml) {
    const int i = blockIdx.x;
    const int j = threadIdx.x;
    float a0 = 0.f, a1 = 0.f, a2 = 0.f, a3 = 0.f;
    #pragma unroll 4
    for (int o = 0; o < C_DIM; o += 4) {
        a0 = fmaf(Wq[(o + 0) * C_DIM + i], Wk[(o + 0) * C_DIM + j], a0);
        a1 = fmaf(Wq[(o + 1) * C_DIM + i], Wk[(o + 1) * C_DIM + j], a1);
        a2 = fmaf(Wq[(o + 2) * C_DIM + i], Wk[(o + 2) * C_DIM + j], a2);
        a3 = fmaf(Wq[(o + 3) * C_DIM + i], Wk[(o + 3) * C_DIM + j], a3);
    }
    float acc = (a0 + a1) + (a2 + a3);
    unsigned short h, l;
    split2(acc, h, l);
    Mh[i * C_DIM + j] = h;
    Ml[i * C_DIM + j] = l;
}

// ---------------------------------------------------------------------------
// K2: score[v][p] = q[v,:,p]^T M k[v,:,p], 3-term split-bf16 MFMA.
// v6: OCCUPANCY-FIRST. 512 thr = 8 waves; wave w owns i-rows [32w, 32w+32)
// -> acc[2][4] = 32 AGPR/thread (was 64). A-fragments in-loop from L2
// (32 VGPR, no pipeline; covered by 4 waves/SIMD cross-block stagger).
// Term order AhBh -> AlBh -> AhBl keeps Bh/Bl liveness disjoint.
// __launch_bounds__(512,4) caps unified VGPR at 128 -> 2 blocks/CU.
// K tile double-buffered in LDS, conflict-free staging, 1 barrier per ks.
// ---------------------------------------------------------------------------
__global__ __launch_bounds__(512, 4) void score_kernel(
        const float* __restrict__ q, const float* __restrict__ k,
        const unsigned short* __restrict__ Mh,
        const unsigned short* __restrict__ Ml,
        float* __restrict__ score) {
    const int tid  = threadIdx.x;
    const int lane = tid & 63;          // also the staging pixel
    const int w    = tid >> 6;          // wave 0..7; also staging ch-group
    const int pt   = blockIdx.x & 255;
    const int v    = blockIdx.x >> 8;
    const int gp0  = pt * PT;
    const int l15  = lane & 15;
    const int l4   = lane >> 4;

    __shared__ __align__(16) unsigned short Kh_s[2][PT * KROW];  // 2x5 KB
    __shared__ __align__(16) unsigned short Kl_s[2][PT * KROW];  // 2x5 KB
    __shared__ float s_red[8][PT];                               // 2 KB

    const float* kv = k + (size_t)v * C_DIM * HW + gp0;
    const float* qv = q + (size_t)v * C_DIM * HW + gp0;
    const int ibase = w * 32;

    f32x4 acc[2][4];
    #pragma unroll
    for (int a = 0; a < 2; ++a)
        #pragma unroll
        for (int b = 0; b < 4; ++b)
            acc[a][b] = (f32x4){0.f, 0.f, 0.f, 0.f};

    // ---- prologue: stage K(ks=0) into buf 0 (4 channels per thread) ----
    {
        const float* kp = kv + (size_t)(w * 4) * HW + lane;
        float x[4];
        #pragma unroll
        for (int e = 0; e < 4; ++e) x[e] = kp[(size_t)e * HW];
        unsigned short h[4], l[4];
        #pragma unroll
        for (int e = 0; e < 4; ++e) split2(x[e], h[e], l[e]);
        uint2 H, L;
        H.x = (unsigned)h[0] | ((unsigned)h[1] << 16);
        H.y = (unsigned)h[2] | ((unsigned)h[3] << 16);
        L.x = (unsigned)l[0] | ((unsigned)l[1] << 16);
        L.y = (unsigned)l[2] | ((unsigned)l[3] << 16);
        *(uint2*)&Kh_s[0][lane * KROW + w * 4] = H;
        *(uint2*)&Kl_s[0][lane * KROW + w * 4] = L;
    }
    __syncthreads();

    #pragma unroll 2
    for (int ks = 0; ks < 8; ++ks) {
        const int cur = ks & 1;

        // (1) issue next K-tile loads first (HBM latency rides under MFMA)
        float x[4];
        if (ks < 7) {
            const float* kp = kv + (size_t)((ks + 1) * BK + w * 4) * HW + lane;
            #pragma unroll
            for (int e = 0; e < 4; ++e) x[e] = kp[(size_t)e * HW];
        }

        // (2) A fragments in-loop from global (M hi/lo, L2-hot)
        bf16x8 Ah[2], Al[2];
        #pragma unroll
        for (int it = 0; it < 2; ++it) {
            int row = ibase + it * 16 + l15;
            Ah[it] = *(const bf16x8*)(Mh + (size_t)row * C_DIM + ks * BK + l4 * 8);
            Al[it] = *(const bf16x8*)(Ml + (size_t)row * C_DIM + ks * BK + l4 * 8);
        }

        // (3) B fragments from LDS; terms ordered so Bh dies before Bl peaks
        bf16x8 Bh[4];
        #pragma unroll
        for (int jt = 0; jt < 4; ++jt) {
            int bp = jt * 16 + l15;
            Bh[jt] = *(const bf16x8*)&Kh_s[cur][bp * KROW + l4 * 8];
        }
        #pragma unroll
        for (int it = 0; it < 2; ++it)
            #pragma unroll
            for (int jt = 0; jt < 4; ++jt)
                acc[it][jt] = __builtin_amdgcn_mfma_f32_16x16x32_bf16(
                                  Ah[it], Bh[jt], acc[it][jt], 0, 0, 0);
        #pragma unroll
        for (int it = 0; it < 2; ++it)
            #pragma unroll
            for (int jt = 0; jt < 4; ++jt)
                acc[it][jt] = __builtin_amdgcn_mfma_f32_16x16x32_bf16(
                                  Al[it], Bh[jt], acc[it][jt], 0, 0, 0);
        bf16x8 Bl[4];
        #pragma unroll
        for (int jt = 0; jt < 4; ++jt) {
            int bp = jt * 16 + l15;
            Bl[jt] = *(const bf16x8*)&Kl_s[cur][bp * KROW + l4 * 8];
        }
        #pragma unroll
        for (int it = 0; it < 2; ++it)
            #pragma unroll
            for (int jt = 0; jt < 4; ++jt)
                acc[it][jt] = __builtin_amdgcn_mfma_f32_16x16x32_bf16(
                                  Ah[it], Bl[jt], acc[it][jt], 0, 0, 0);

        // (4) split + write next K buffer
        if (ks < 7) {
            unsigned short h[4], l[4];
            #pragma unroll
            for (int e = 0; e < 4; ++e) split2(x[e], h[e], l[e]);
            uint2 H, L;
            H.x = (unsigned)h[0] | ((unsigned)h[1] << 16);
            H.y = (unsigned)h[2] | ((unsigned)h[3] << 16);
            L.x = (unsigned)l[0] | ((unsigned)l[1] << 16);
            L.y = (unsigned)l[2] | ((unsigned)l[3] << 16);
            *(uint2*)&Kh_s[cur ^ 1][lane * KROW + w * 4] = H;
            *(uint2*)&Kl_s[cur ^ 1][lane * KROW + w * 4] = L;
        }
        __syncthreads();
    }

    // ---- epilogue: sp[p] = sum_i q[i,p] * T[i,p] over this wave's 32 rows ----
    float sp[4];
    #pragma unroll
    for (int jt = 0; jt < 4; ++jt) sp[jt] = 0.f;
    #pragma unroll
    for (int jt = 0; jt < 4; ++jt) {
        #pragma unroll
        for (int it = 0; it < 2; ++it) {
            int irow = ibase + it * 16 + l4 * 4;
            const float* qp = qv + (size_t)irow * HW + jt * 16 + l15;
            #pragma unroll
            for (int r = 0; r < 4; ++r)
                sp[jt] = fmaf(qp[(size_t)r * HW], acc[it][jt][r], sp[jt]);
        }
        sp[jt] += __shfl_xor(sp[jt], 16, 64);
        sp[jt] += __shfl_xor(sp[jt], 32, 64);
    }
    if (lane < 16) {
        #pragma unroll
        for (int jt = 0; jt < 4; ++jt)
            s_red[w][jt * 16 + lane] = sp[jt];
    }
    __syncthreads();
    if (tid < PT) {
        float s = 0.f;
        #pragma unroll
        for (int ww = 0; ww < 8; ++ww) s += s_red[ww][tid];
        score[v * HW + gp0 + tid] = s;
    }
}

// ---------------------------------------------------------------------------
// K3: in-place softmax over views.
// ---------------------------------------------------------------------------
__global__ __launch_bounds__(256) void softmax_w_kernel(float* __restrict__ score) {
    const int p = blockIdx.x * 256 + threadIdx.x;
    float s[V_DIM];
    float mx = -1e30f;
    #pragma unroll
    for (int vv = 0; vv < V_DIM; ++vv) {
        s[vv] = score[vv * HW + p];
        mx = fmaxf(mx, s[vv]);
    }
    float sum = 0.f;
    #pragma unroll
    for (int vv = 0; vv < V_DIM; ++vv) {
        s[vv] = __expf(s[vv] - mx);
        sum += s[vv];
    }
    float inv = 1.0f / sum;
    #pragma unroll
    for (int vv = 0; vv < V_DIM; ++vv)
        score[vv * HW + p] = s[vv] * inv;
}

// ---------------------------------------------------------------------------
// K4: split Wv into bf16 hi/lo (reuses the Mh/Ml workspace).
// ---------------------------------------------------------------------------
__global__ void wsplit_kernel(const float* __restrict__ Wv,
                              unsigned short* __restrict__ Wvh,
                              unsigned short* __restrict__ Wvl) {
    const int i = blockIdx.x;
    const int j = threadIdx.x;
    unsigned short h, l;
    split2(Wv[i * C_DIM + j], h, l);
    Wvh[i * C_DIM + j] = h;
    Wvl[i * C_DIM + j] = l;
}

// ---------------------------------------------------------------------------
// K5: out = Wv @ vbar, vbar[c][p] = sum_v w[v][p]*v[v][c][p].  (unchanged
// from round 5 — not the current bottleneck; one experiment at a time.)
// ---------------------------------------------------------------------------
__global__ __launch_bounds__(512, 2) void out_gemm_kernel(
        const float* __restrict__ vin,
        const unsigned short* __restrict__ Wvh,
        const unsigned short* __restrict__ Wvl,
        const float* __restrict__ wsm,
        float* __restrict__ out) {
    const int tid  = threadIdx.x;
    const int lane = tid & 63;
    const int w    = tid >> 6;          // 0..7
    const int gp0  = blockIdx.x * PT;
    const int l15  = lane & 15;
    const int l4   = lane >> 4;
    const int p_s  = tid & 63;
    const int jg   = tid >> 6;

    __shared__ __align__(16) unsigned short Xh_s[2][PT * KROW];
    __shared__ __align__(16) unsigned short Xl_s[2][PT * KROW];

    float wr[V_DIM];
    #pragma unroll
    for (int vv = 0; vv < V_DIM; ++vv) wr[vv] = wsm[vv * HW + gp0 + p_s];

    const float* vbase = vin + gp0 + p_s;
    const int obase = w * 32;

    f32x4 acc[2][4];
    #pragma unroll
    for (int a = 0; a < 2; ++a)
        #pragma unroll
        for (int b = 0; b < 4; ++b)
            acc[a][b] = (f32x4){0.f, 0.f, 0.f, 0.f};

    bf16x8 Ah[2][2], Al[2][2];

    // ---- prologue ----
    {
        float xv[4][V_DIM];
        #pragma unroll
        for (int vv = 0; vv < V_DIM; ++vv)
            #pragma unroll
            for (int e = 0; e < 4; ++e)
                xv[e][vv] = vbase[(size_t)(vv * C_DIM + jg * 4 + e) * HW];
        unsigned short h[4], l[4];
        #pragma unroll
        for (int e = 0; e < 4; ++e) {
            float s = 0.f;
            #pragma unroll
            for (int vv = 0; vv < V_DIM; ++vv) s = fmaf(wr[vv], xv[e][vv], s);
            split2(s, h[e], l[e]);
        }
        uint2 H, L;
        H.x = (unsigned)h[0] | ((unsigned)h[1] << 16);
        H.y = (unsigned)h[2] | ((unsigned)h[3] << 16);
        L.x = (unsigned)l[0] | ((unsigned)l[1] << 16);
        L.y = (unsigned)l[2] | ((unsigned)l[3] << 16);
        *(uint2*)&Xh_s[0][p_s * KROW + jg * 4] = H;
        *(uint2*)&Xl_s[0][p_s * KROW + jg * 4] = L;

        #pragma unroll
        for (int it = 0; it < 2; ++it) {
            int row = obase + it * 16 + l15;
            Ah[0][it] = *(const bf16x8*)(Wvh + (size_t)row * C_DIM + l4 * 8);
            Al[0][it] = *(const bf16x8*)(Wvl + (size_t)row * C_DIM + l4 * 8);
        }
    }
    __syncthreads();

    #pragma unroll
    for (int ks = 0; ks < 8; ++ks) {
        const int cur = ks & 1;

        float xv[4][V_DIM];
        if (ks < 7) {
            #pragma unroll
            for (int vv = 0; vv < V_DIM; ++vv)
                #pragma unroll
                for (int e = 0; e < 4; ++e)
                    xv[e][vv] = vbase[(size_t)(vv * C_DIM + (ks + 1) * BK +
                                               jg * 4 + e) * HW];
            #pragma unroll
            for (int it = 0; it < 2; ++it) {
                int row = obase + it * 16 + l15;
                Ah[cur ^ 1][it] = *(const bf16x8*)(Wvh + (size_t)row * C_DIM +
                                                   (ks + 1) * BK + l4 * 8);
                Al[cur ^ 1][it] = *(const bf16x8*)(Wvl + (size_t)row * C_DIM +
                                                   (ks + 1) * BK + l4 * 8);
            }
        }

        bf16x8 Bh[4], Bl[4];
        #pragma unroll
        for (int jt = 0; jt < 4; ++jt) {
            int bp = jt * 16 + l15;
            Bh[jt] = *(const bf16x8*)&Xh_s[cur][bp * KROW + l4 * 8];
            Bl[jt] = *(const bf16x8*)&Xl_s[cur][bp * KROW + l4 * 8];
        }

        #pragma unroll
        for (int it = 0; it < 2; ++it)
            #pragma unroll
            for (int jt = 0; jt < 4; ++jt)
                acc[it][jt] = __builtin_amdgcn_mfma_f32_16x16x32_bf16(
                                  Ah[cur][it], Bh[jt], acc[it][jt], 0, 0, 0);
        #pragma unroll
        for (int it = 0; it < 2; ++it)
            #pragma unroll
            for (int jt = 0; jt < 4; ++jt)
                acc[it][jt] = __builtin_amdgcn_mfma_f32_16x16x32_bf16(
                                  Ah[cur][it], Bl[jt], acc[it][jt], 0, 0, 0);
        #pragma unroll
        for (int it = 0; it < 2; ++it)
            #pragma unroll
            for (int jt = 0; jt < 4; ++jt)
                acc[it][jt] = __builtin_amdgcn_mfma_f32_16x16x32_bf16(
                                  Al[cur][it], Bh[jt], acc[it][jt], 0, 0, 0);

        if (ks < 7) {
            unsigned short h[4], l[4];
            #pragma unroll
            for (int e = 0; e < 4; ++e) {
                float s = 0.f;
                #pragma unroll
                for (int vv = 0; vv < V_DIM; ++vv) s = fmaf(wr[vv], xv[e][vv], s);
                split2(s, h[e], l[e]);
            }
            uint2 H, L;
            H.x = (unsigned)h[0] | ((unsigned)h[1] << 16);
            H.y = (unsigned)h[2] | ((unsigned)h[3] << 16);
            L.x = (unsigned)l[0] | ((unsigned)l[1] << 16);
            L.y = (unsigned)l[2] | ((unsigned)l[3] << 16);
            *(uint2*)&Xh_s[cur ^ 1][p_s * KROW + jg * 4] = H;
            *(uint2*)&Xl_s[cur ^ 1][p_s * KROW + jg * 4] = L;
        }
        __syncthreads();
    }

    #pragma unroll
    for (int it = 0; it < 2; ++it)
        #pragma unroll
        for (int jt = 0; jt < 4; ++jt)
            #pragma unroll
            for (int r = 0; r < 4; ++r) {
                int o = obase + it * 16 + l4 * 4 + r;
                out[(size_t)o * HW + gp0 + jt * 16 + l15] = acc[it][jt][r];
            }
}

// ---------------------------------------------------------------------------
extern "C" void kernel_launch(void* const* d_in, const int* in_sizes, int n_in,
                              void* d_out, int out_size, void* d_ws, size_t ws_size,
                              hipStream_t stream) {
    const float* q  = (const float*)d_in[0];
    const float* k  = (const float*)d_in[1];
    const float* v  = (const float*)d_in[2];
    const float* Wq = (const float*)d_in[3];
    const float* Wk = (const float*)d_in[4];
    const float* Wv = (const float*)d_in[5];
    float* out = (float*)d_out;

    unsigned short* Mh = (unsigned short*)d_ws;          // 128 KB (later: Wvh)
    unsigned short* Ml = Mh + C_DIM * C_DIM;             // 128 KB (later: Wvl)
    float* score = (float*)(Ml + C_DIM * C_DIM);         // 384 KB (-> weights)

    compute_M_kernel<<<C_DIM, C_DIM, 0, stream>>>(Wq, Wk, Mh, Ml);
    score_kernel<<<V_DIM * 256, 512, 0, stream>>>(q, k, Mh, Ml, score);
    softmax_w_kernel<<<HW / 256, 256, 0, stream>>>(score);
    wsplit_kernel<<<C_DIM, C_DIM, 0, stream>>>(Wv, Mh, Ml);
    out_gemm_kernel<<<HW / PT, 512, 0, stream>>>(v, Mh, Ml, score, out);
}

// Round 7
// 125.294 us; speedup vs baseline: 1.2164x; 1.0906x over previous
//
#include <hip/hip_runtime.h>
#include <math.h>

#define HW 16384
#define C_DIM 256
#define V_DIM 6
#define PT 64
#define BK 32
#define KROW 40

typedef short bf16x8 __attribute__((ext_vector_type(8)));
typedef float f32x4 __attribute__((ext_vector_type(4)));

// fp32 -> bf16 hi/lo split (truncation). |x - (hi+lo)| <= 2^-16 |x|.
__device__ __forceinline__ void split2(float x, unsigned short& h,
                                       unsigned short& l) {
    unsigned u = __float_as_uint(x);
    h = (unsigned short)(u >> 16);
    float xl = x - __uint_as_float(u & 0xFFFF0000u);
    l = (unsigned short)(__float_as_uint(xl) >> 16);
}

// ---------------------------------------------------------------------------
// K1: M = Wq^T @ Wk, stored as bf16 hi/lo.
// ---------------------------------------------------------------------------
__global__ void compute_M_kernel(const float* __restrict__ Wq,
                                 const float* __restrict__ Wk,
                                 unsigned short* __restrict__ Mh,
                                 unsigned short* __restrict__ Ml) {
    const int i = blockIdx.x;
    const int j = threadIdx.x;
    float a0 = 0.f, a1 = 0.f, a2 = 0.f, a3 = 0.f;
    #pragma unroll 4
    for (int o = 0; o < C_DIM; o += 4) {
        a0 = fmaf(Wq[(o + 0) * C_DIM + i], Wk[(o + 0) * C_DIM + j], a0);
        a1 = fmaf(Wq[(o + 1) * C_DIM + i], Wk[(o + 1) * C_DIM + j], a1);
        a2 = fmaf(Wq[(o + 2) * C_DIM + i], Wk[(o + 2) * C_DIM + j], a2);
        a3 = fmaf(Wq[(o + 3) * C_DIM + i], Wk[(o + 3) * C_DIM + j], a3);
    }
    float acc = (a0 + a1) + (a2 + a3);
    unsigned short h, l;
    split2(acc, h, l);
    Mh[i * C_DIM + j] = h;
    Ml[i * C_DIM + j] = l;
}

// ---------------------------------------------------------------------------
// K2 v7: score[v][p] = q[v,:,p]^T M k[v,:,p], 3-term split-bf16 MFMA.
// 512 thr = 8 waves; wave w owns i-rows [32w, 32w+32) -> acc[2][4] = 32 AGPR.
// LATENCY FIX vs r6:
//   * k-prefetch DEPTH 2: tile ks+2 loaded at iter ks into reg set kx[ks&1];
//     split+LDS-write of tile ks+1 uses regs loaded a full iteration ago.
//   * A-fragments (M hi/lo from L2) REGISTER-PIPELINED depth 1, issued
//     BEFORE the k loads -> MFMA's waitcnt never drains the HBM prefetch.
// K tile double-buffered in LDS (buf[t&1] holds tile t), 1 barrier per ks.
// ---------------------------------------------------------------------------
__global__ __launch_bounds__(512, 4) void score_kernel(
        const float* __restrict__ q, const float* __restrict__ k,
        const unsigned short* __restrict__ Mh,
        const unsigned short* __restrict__ Ml,
        float* __restrict__ score) {
    const int tid  = threadIdx.x;
    const int lane = tid & 63;          // also the staging pixel
    const int w    = tid >> 6;          // wave 0..7; also staging ch-group
    const int pt   = blockIdx.x & 255;
    const int v    = blockIdx.x >> 8;
    const int gp0  = pt * PT;
    const int l15  = lane & 15;
    const int l4   = lane >> 4;

    __shared__ __align__(16) unsigned short Kh_s[2][PT * KROW];  // 2x5 KB
    __shared__ __align__(16) unsigned short Kl_s[2][PT * KROW];  // 2x5 KB
    __shared__ float s_red[8][PT];                               // 2 KB

    const float* kv = k + (size_t)v * C_DIM * HW + gp0;
    const float* qv = q + (size_t)v * C_DIM * HW + gp0;
    const int ibase = w * 32;

    f32x4 acc[2][4];
    #pragma unroll
    for (int a = 0; a < 2; ++a)
        #pragma unroll
        for (int b = 0; b < 4; ++b)
            acc[a][b] = (f32x4){0.f, 0.f, 0.f, 0.f};

    float kx[2][4];          // k prefetch, depth 2 (tile t in kx[t&1])
    bf16x8 Ah[2][2], Al[2][2];   // A pipeline, depth 1 (tile t in set t&1)

    // ---- prologue ----
    {
        // tile 0 -> split -> LDS buf 0
        const float* kp = kv + (size_t)(w * 4) * HW + lane;
        float x[4];
        #pragma unroll
        for (int e = 0; e < 4; ++e) x[e] = kp[(size_t)e * HW];
        unsigned short h[4], l[4];
        #pragma unroll
        for (int e = 0; e < 4; ++e) split2(x[e], h[e], l[e]);
        uint2 H, L;
        H.x = (unsigned)h[0] | ((unsigned)h[1] << 16);
        H.y = (unsigned)h[2] | ((unsigned)h[3] << 16);
        L.x = (unsigned)l[0] | ((unsigned)l[1] << 16);
        L.y = (unsigned)l[2] | ((unsigned)l[3] << 16);
        *(uint2*)&Kh_s[0][lane * KROW + w * 4] = H;
        *(uint2*)&Kl_s[0][lane * KROW + w * 4] = L;

        // tile 1 -> regs kx[1]
        const float* kp1 = kv + (size_t)(BK + w * 4) * HW + lane;
        #pragma unroll
        for (int e = 0; e < 4; ++e) kx[1][e] = kp1[(size_t)e * HW];

        // A(0) -> set 0
        #pragma unroll
        for (int it = 0; it < 2; ++it) {
            int row = ibase + it * 16 + l15;
            Ah[0][it] = *(const bf16x8*)(Mh + (size_t)row * C_DIM + l4 * 8);
            Al[0][it] = *(const bf16x8*)(Ml + (size_t)row * C_DIM + l4 * 8);
        }
    }
    __syncthreads();

    #pragma unroll
    for (int ks = 0; ks < 8; ++ks) {
        const int cur = ks & 1;

        // (1) A(ks+1) first (L2, shallow) ...
        if (ks < 7) {
            #pragma unroll
            for (int it = 0; it < 2; ++it) {
                int row = ibase + it * 16 + l15;
                Ah[cur ^ 1][it] = *(const bf16x8*)(Mh + (size_t)row * C_DIM +
                                                   (ks + 1) * BK + l4 * 8);
                Al[cur ^ 1][it] = *(const bf16x8*)(Ml + (size_t)row * C_DIM +
                                                   (ks + 1) * BK + l4 * 8);
            }
        }
        // (2) ... then k(ks+2) (HBM, deep) into the set tile ks vacated
        if (ks < 6) {
            const float* kp = kv + (size_t)((ks + 2) * BK + w * 4) * HW + lane;
            #pragma unroll
            for (int e = 0; e < 4; ++e) kx[cur][e] = kp[(size_t)e * HW];
        }

        // (3) B fragments from LDS + MFMAs (A from LAST iteration's loads;
        //     its waitcnt leaves the newer k loads in flight)
        bf16x8 Bh[4];
        #pragma unroll
        for (int jt = 0; jt < 4; ++jt) {
            int bp = jt * 16 + l15;
            Bh[jt] = *(const bf16x8*)&Kh_s[cur][bp * KROW + l4 * 8];
        }
        #pragma unroll
        for (int it = 0; it < 2; ++it)
            #pragma unroll
            for (int jt = 0; jt < 4; ++jt)
                acc[it][jt] = __builtin_amdgcn_mfma_f32_16x16x32_bf16(
                                  Ah[cur][it], Bh[jt], acc[it][jt], 0, 0, 0);
        #pragma unroll
        for (int it = 0; it < 2; ++it)
            #pragma unroll
            for (int jt = 0; jt < 4; ++jt)
                acc[it][jt] = __builtin_amdgcn_mfma_f32_16x16x32_bf16(
                                  Al[cur][it], Bh[jt], acc[it][jt], 0, 0, 0);
        bf16x8 Bl[4];
        #pragma unroll
        for (int jt = 0; jt < 4; ++jt) {
            int bp = jt * 16 + l15;
            Bl[jt] = *(const bf16x8*)&Kl_s[cur][bp * KROW + l4 * 8];
        }
        #pragma unroll
        for (int it = 0; it < 2; ++it)
            #pragma unroll
            for (int jt = 0; jt < 4; ++jt)
                acc[it][jt] = __builtin_amdgcn_mfma_f32_16x16x32_bf16(
                                  Ah[cur][it], Bl[jt], acc[it][jt], 0, 0, 0);

        // (4) split tile ks+1 (regs loaded at iter ks-1 -> long since landed)
        //     and write to the LDS buffer the MFMAs just vacated
        if (ks < 7) {
            unsigned short h[4], l[4];
            #pragma unroll
            for (int e = 0; e < 4; ++e) split2(kx[cur ^ 1][e], h[e], l[e]);
            uint2 H, L;
            H.x = (unsigned)h[0] | ((unsigned)h[1] << 16);
            H.y = (unsigned)h[2] | ((unsigned)h[3] << 16);
            L.x = (unsigned)l[0] | ((unsigned)l[1] << 16);
            L.y = (unsigned)l[2] | ((unsigned)l[3] << 16);
            *(uint2*)&Kh_s[cur ^ 1][lane * KROW + w * 4] = H;
            *(uint2*)&Kl_s[cur ^ 1][lane * KROW + w * 4] = L;
        }
        __syncthreads();
    }

    // ---- epilogue: sp[p] = sum_i q[i,p] * T[i,p] over this wave's 32 rows ----
    float sp[4];
    #pragma unroll
    for (int jt = 0; jt < 4; ++jt) sp[jt] = 0.f;
    #pragma unroll
    for (int jt = 0; jt < 4; ++jt) {
        #pragma unroll
        for (int it = 0; it < 2; ++it) {
            int irow = ibase + it * 16 + l4 * 4;
            const float* qp = qv + (size_t)irow * HW + jt * 16 + l15;
            #pragma unroll
            for (int r = 0; r < 4; ++r)
                sp[jt] = fmaf(qp[(size_t)r * HW], acc[it][jt][r], sp[jt]);
        }
        sp[jt] += __shfl_xor(sp[jt], 16, 64);
        sp[jt] += __shfl_xor(sp[jt], 32, 64);
    }
    if (lane < 16) {
        #pragma unroll
        for (int jt = 0; jt < 4; ++jt)
            s_red[w][jt * 16 + lane] = sp[jt];
    }
    __syncthreads();
    if (tid < PT) {
        float s = 0.f;
        #pragma unroll
        for (int ww = 0; ww < 8; ++ww) s += s_red[ww][tid];
        score[v * HW + gp0 + tid] = s;
    }
}

// ---------------------------------------------------------------------------
// K3: in-place softmax over views.
// ---------------------------------------------------------------------------
__global__ __launch_bounds__(256) void softmax_w_kernel(float* __restrict__ score) {
    const int p = blockIdx.x * 256 + threadIdx.x;
    float s[V_DIM];
    float mx = -1e30f;
    #pragma unroll
    for (int vv = 0; vv < V_DIM; ++vv) {
        s[vv] = score[vv * HW + p];
        mx = fmaxf(mx, s[vv]);
    }
    float sum = 0.f;
    #pragma unroll
    for (int vv = 0; vv < V_DIM; ++vv) {
        s[vv] = __expf(s[vv] - mx);
        sum += s[vv];
    }
    float inv = 1.0f / sum;
    #pragma unroll
    for (int vv = 0; vv < V_DIM; ++vv)
        score[vv * HW + p] = s[vv] * inv;
}

// ---------------------------------------------------------------------------
// K4: split Wv into bf16 hi/lo (reuses the Mh/Ml workspace).
// ---------------------------------------------------------------------------
__global__ void wsplit_kernel(const float* __restrict__ Wv,
                              unsigned short* __restrict__ Wvh,
                              unsigned short* __restrict__ Wvl) {
    const int i = blockIdx.x;
    const int j = threadIdx.x;
    unsigned short h, l;
    split2(Wv[i * C_DIM + j], h, l);
    Wvh[i * C_DIM + j] = h;
    Wvl[i * C_DIM + j] = l;
}

// ---------------------------------------------------------------------------
// K5: out = Wv @ vbar, vbar[c][p] = sum_v w[v][p]*v[v][c][p].  (unchanged —
// not the current bottleneck; one experiment at a time.)
// ---------------------------------------------------------------------------
__global__ __launch_bounds__(512, 2) void out_gemm_kernel(
        const float* __restrict__ vin,
        const unsigned short* __restrict__ Wvh,
        const unsigned short* __restrict__ Wvl,
        const float* __restrict__ wsm,
        float* __restrict__ out) {
    const int tid  = threadIdx.x;
    const int lane = tid & 63;
    const int w    = tid >> 6;          // 0..7
    const int gp0  = blockIdx.x * PT;
    const int l15  = lane & 15;
    const int l4   = lane >> 4;
    const int p_s  = tid & 63;
    const int jg   = tid >> 6;

    __shared__ __align__(16) unsigned short Xh_s[2][PT * KROW];
    __shared__ __align__(16) unsigned short Xl_s[2][PT * KROW];

    float wr[V_DIM];
    #pragma unroll
    for (int vv = 0; vv < V_DIM; ++vv) wr[vv] = wsm[vv * HW + gp0 + p_s];

    const float* vbase = vin + gp0 + p_s;
    const int obase = w * 32;

    f32x4 acc[2][4];
    #pragma unroll
    for (int a = 0; a < 2; ++a)
        #pragma unroll
        for (int b = 0; b < 4; ++b)
            acc[a][b] = (f32x4){0.f, 0.f, 0.f, 0.f};

    bf16x8 Ah[2][2], Al[2][2];

    // ---- prologue ----
    {
        float xv[4][V_DIM];
        #pragma unroll
        for (int vv = 0; vv < V_DIM; ++vv)
            #pragma unroll
            for (int e = 0; e < 4; ++e)
                xv[e][vv] = vbase[(size_t)(vv * C_DIM + jg * 4 + e) * HW];
        unsigned short h[4], l[4];
        #pragma unroll
        for (int e = 0; e < 4; ++e) {
            float s = 0.f;
            #pragma unroll
            for (int vv = 0; vv < V_DIM; ++vv) s = fmaf(wr[vv], xv[e][vv], s);
            split2(s, h[e], l[e]);
        }
        uint2 H, L;
        H.x = (unsigned)h[0] | ((unsigned)h[1] << 16);
        H.y = (unsigned)h[2] | ((unsigned)h[3] << 16);
        L.x = (unsigned)l[0] | ((unsigned)l[1] << 16);
        L.y = (unsigned)l[2] | ((unsigned)l[3] << 16);
        *(uint2*)&Xh_s[0][p_s * KROW + jg * 4] = H;
        *(uint2*)&Xl_s[0][p_s * KROW + jg * 4] = L;

        #pragma unroll
        for (int it = 0; it < 2; ++it) {
            int row = obase + it * 16 + l15;
            Ah[0][it] = *(const bf16x8*)(Wvh + (size_t)row * C_DIM + l4 * 8);
            Al[0][it] = *(const bf16x8*)(Wvl + (size_t)row * C_DIM + l4 * 8);
        }
    }
    __syncthreads();

    #pragma unroll
    for (int ks = 0; ks < 8; ++ks) {
        const int cur = ks & 1;

        float xv[4][V_DIM];
        if (ks < 7) {
            #pragma unroll
            for (int vv = 0; vv < V_DIM; ++vv)
                #pragma unroll
                for (int e = 0; e < 4; ++e)
                    xv[e][vv] = vbase[(size_t)(vv * C_DIM + (ks + 1) * BK +
                                               jg * 4 + e) * HW];
            #pragma unroll
            for (int it = 0; it < 2; ++it) {
                int row = obase + it * 16 + l15;
                Ah[cur ^ 1][it] = *(const bf16x8*)(Wvh + (size_t)row * C_DIM +
                                                   (ks + 1) * BK + l4 * 8);
                Al[cur ^ 1][it] = *(const bf16x8*)(Wvl + (size_t)row * C_DIM +
                                                   (ks + 1) * BK + l4 * 8);
            }
        }

        bf16x8 Bh[4], Bl[4];
        #pragma unroll
        for (int jt = 0; jt < 4; ++jt) {
            int bp = jt * 16 + l15;
            Bh[jt] = *(const bf16x8*)&Xh_s[cur][bp * KROW + l4 * 8];
            Bl[jt] = *(const bf16x8*)&Xl_s[cur][bp * KROW + l4 * 8];
        }

        #pragma unroll
        for (int it = 0; it < 2; ++it)
            #pragma unroll
            for (int jt = 0; jt < 4; ++jt)
                acc[it][jt] = __builtin_amdgcn_mfma_f32_16x16x32_bf16(
                                  Ah[cur][it], Bh[jt], acc[it][jt], 0, 0, 0);
        #pragma unroll
        for (int it = 0; it < 2; ++it)
            #pragma unroll
            for (int jt = 0; jt < 4; ++jt)
                acc[it][jt] = __builtin_amdgcn_mfma_f32_16x16x32_bf16(
                                  Ah[cur][it], Bl[jt], acc[it][jt], 0, 0, 0);
        #pragma unroll
        for (int it = 0; it < 2; ++it)
            #pragma unroll
            for (int jt = 0; jt < 4; ++jt)
                acc[it][jt] = __builtin_amdgcn_mfma_f32_16x16x32_bf16(
                                  Al[cur][it], Bh[jt], acc[it][jt], 0, 0, 0);

        if (ks < 7) {
            unsigned short h[4], l[4];
            #pragma unroll
            for (int e = 0; e < 4; ++e) {
                float s = 0.f;
                #pragma unroll
                for (int vv = 0; vv < V_DIM; ++vv) s = fmaf(wr[vv], xv[e][vv], s);
                split2(s, h[e], l[e]);
            }
            uint2 H, L;
            H.x = (unsigned)h[0] | ((unsigned)h[1] << 16);
            H.y = (unsigned)h[2] | ((unsigned)h[3] << 16);
            L.x = (unsigned)l[0] | ((unsigned)l[1] << 16);
            L.y = (unsigned)l[2] | ((unsigned)l[3] << 16);
            *(uint2*)&Xh_s[cur ^ 1][p_s * KROW + jg * 4] = H;
            *(uint2*)&Xl_s[cur ^ 1][p_s * KROW + jg * 4] = L;
        }
        __syncthreads();
    }

    #pragma unroll
    for (int it = 0; it < 2; ++it)
        #pragma unroll
        for (int jt = 0; jt < 4; ++jt)
            #pragma unroll
            for (int r = 0; r < 4; ++r) {
                int o = obase + it * 16 + l4 * 4 + r;
                out[(size_t)o * HW + gp0 + jt * 16 + l15] = acc[it][jt][r];
            }
}

// ---------------------------------------------------------------------------
extern "C" void kernel_launch(void* const* d_in, const int* in_sizes, int n_in,
                              void* d_out, int out_size, void* d_ws, size_t ws_size,
                              hipStream_t stream) {
    const float* q  = (const float*)d_in[0];
    const float* k  = (const float*)d_in[1];
    const float* v  = (const float*)d_in[2];
    const float* Wq = (const float*)d_in[3];
    const float* Wk = (const float*)d_in[4];
    const float* Wv = (const float*)d_in[5];
    float* out = (float*)d_out;

    unsigned short* Mh = (unsigned short*)d_ws;          // 128 KB (later: Wvh)
    unsigned short* Ml = Mh + C_DIM * C_DIM;             // 128 KB (later: Wvl)
    float* score = (float*)(Ml + C_DIM * C_DIM);         // 384 KB (-> weights)

    compute_M_kernel<<<C_DIM, C_DIM, 0, stream>>>(Wq, Wk, Mh, Ml);
    score_kernel<<<V_DIM * 256, 512, 0, stream>>>(q, k, Mh, Ml, score);
    softmax_w_kernel<<<HW / 256, 256, 0, stream>>>(score);
    wsplit_kernel<<<C_DIM, C_DIM, 0, stream>>>(Wv, Mh, Ml);
    out_gemm_kernel<<<HW / PT, 512, 0, stream>>>(v, Mh, Ml, score, out);
}